// Round 9
// baseline (252.989 us; speedup 1.0000x reference)
//
#include <hip/hip_runtime.h>
#include <hip/hip_bf16.h>

#define KK 32
#define DD 128
#define NEGV (-1e9f)
#define SE 136   // LDS row stride in ushorts: 272 B, 16-B aligned, non-pow2 banks

typedef __attribute__((ext_vector_type(8))) short bf16x8;
typedef __attribute__((ext_vector_type(4))) float f32x4;

__device__ __forceinline__ unsigned short f2bf(float f) {
    union { float f; unsigned u; } v; v.f = f;
    unsigned r = v.u + 0x7fffu + ((v.u >> 16) & 1u);   // RNE
    return (unsigned short)(r >> 16);
}
__device__ __forceinline__ float bf2f(unsigned short h) {
    union { unsigned u; float f; } v; v.u = ((unsigned)h) << 16;
    return v.f;
}
// packed f32x2 -> bf16x2 (v_cvt_pk_bf16_f32), RNE
__device__ __forceinline__ unsigned pk2(float x, float y) {
    union { __hip_bfloat162 h; unsigned u; } c;
    c.h = __float22bfloat162_rn(float2{x, y});
    return c.u;
}

// ---- prep (one kernel; workspace is re-poisoned each iter, so no sentinel):
//  blocks [0, u2e_blocks): u2e fp32 -> bf16, 64 B/thread (4096 els/block)
//  blocks [u2e_blocks, +192): W1 -> W1t bf16 [n][k], W2 -> W2t bf16 [n][k]
__global__ __launch_bounds__(256) void prep_kernel(
    const float* __restrict__ u2e, const float* __restrict__ W1, const float* __restrict__ W2,
    unsigned short* __restrict__ u2e_bf, unsigned short* __restrict__ W1t,
    unsigned short* __restrict__ W2t, const int u2e_blocks)
{
    const int b = blockIdx.x;
    if (b < u2e_blocks) {
        const long base = (long)b * 4096 + threadIdx.x * 16;
        const float4* s = (const float4*)(u2e + base);
        const float4 v0 = s[0], v1 = s[1], v2 = s[2], v3 = s[3];
        uint4 p0, p1;
        p0.x = pk2(v0.x, v0.y); p0.y = pk2(v0.z, v0.w);
        p0.z = pk2(v1.x, v1.y); p0.w = pk2(v1.z, v1.w);
        p1.x = pk2(v2.x, v2.y); p1.y = pk2(v2.z, v2.w);
        p1.z = pk2(v3.x, v3.y); p1.w = pk2(v3.z, v3.w);
        *(uint4*)(u2e_bf + base)     = p0;
        *(uint4*)(u2e_bf + base + 8) = p1;
    } else {
        const int id = (b - u2e_blocks) * 256 + threadIdx.x;   // 0..49151
        if (id < 256 * 128) {
            const int n = id >> 8, k = id & 255;
            W1t[id] = f2bf(W1[k * DD + n]);
        } else {
            const int j = id - 256 * 128;
            const int n = j >> 7, k = j & 127;
            W2t[j] = f2bf(W2[k * DD + n]);
        }
    }
}

// 512-thread / 8-wave variant: each wave owns 16 output cols (nt gone).
// Same tiles, same barrier chain, same staging volume as the 124-us R4
// kernel -- but 16 waves/CU instead of 8 for latency hiding.
template<bool BF>
__global__ __launch_bounds__(512, 4) void ppagg_mfma(
    const int* __restrict__ nodes, const int* __restrict__ neigh,
    const int* __restrict__ degrees, const float* __restrict__ u2e,
    const unsigned short* __restrict__ u2e_bf,
    const unsigned short* __restrict__ W1t, const unsigned short* __restrict__ W2t,
    const float* __restrict__ b1, const float* __restrict__ b2,
    const float* __restrict__ W3, const float* __restrict__ b3,
    float* __restrict__ out, const int Nn)
{
    __shared__ __align__(16) unsigned short s_A[128 * SE];   // 34.8 KB
    __shared__ __align__(16) unsigned short s_B[128 * SE];   // 34.8 KB
    __shared__ __align__(16) unsigned short s_x8[8 * DD];    // all 8 self vecs bf16 (2 KB)
    __shared__ float s_part[8][128];                          // per-wave logit partials (4 KB)
    __shared__ float s_att[128];

    const int tid  = threadIdx.x;
    const int w    = tid >> 6;     // wave id 0..7
    const int lane = tid & 63;
    const int ln   = lane & 15;
    const int q    = lane >> 4;    // quad

    const int nb = blockIdx.x * 8;
    const int c  = w * 16 + ln;    // owned output col (one 16-col strip per wave)

    const int r  = tid >> 2;       // staged row (0..127)
    const int qt = tid & 3;        // quarter of the row (32 ushorts = 64 B)

    // ---- prologue: both iters' indices + validity ----
    // deg gating: slots k >= deg have exactly-zero attention (NEG logit ->
    // exp underflow -> att == 0.0f) -> skip their gather, stage zeros.
    int idxA, idxB, vA, vB;
    {
        int ng0 = nb + (r >> 5);       if (ng0 >= Nn) ng0 = Nn - 1;
        int ng1 = nb + 4 + (r >> 5);   if (ng1 >= Nn) ng1 = Nn - 1;
        idxA = neigh[ng0 * KK + (r & 31)];
        idxB = neigh[ng1 * KK + (r & 31)];
        vA = (r & 31) < degrees[ng0];
        vB = (r & 31) < degrees[ng1];
    }

    // ---- stage: quarter-row per thread, load -> immediate ds_write ----
    auto stage = [&](unsigned short* buf, int idx, int v) {
        unsigned short* dst = buf + r * SE + qt * 32;
        if (BF && v) {
            const uint4* src = (const uint4*)(u2e_bf + (long)idx * DD + qt * 32);
            #pragma unroll
            for (int cc = 0; cc < 4; ++cc) *(uint4*)(dst + cc * 8) = src[cc];
        } else if (!BF && v) {
            const float4* src = (const float4*)(u2e + (long)idx * DD + qt * 32);
            #pragma unroll
            for (int c8 = 0; c8 < 4; ++c8) {
                const float4 v0 = src[c8 * 2];
                const float4 v1 = src[c8 * 2 + 1];
                uint4 p;
                p.x = pk2(v0.x, v0.y); p.y = pk2(v0.z, v0.w);
                p.z = pk2(v1.x, v1.y); p.w = pk2(v1.z, v1.w);
                *(uint4*)(dst + c8 * 8) = p;
            }
        } else {
            const uint4 z = {0u, 0u, 0u, 0u};
            #pragma unroll
            for (int cc = 0; cc < 4; ++cc) *(uint4*)(dst + cc * 8) = z;
        }
    };

    // ---- it0 stage into s_A (issues first: longest-latency loads) ----
    stage(s_A, idxA, vA);

    // ---- self vectors: wave w owns node nb+w -> s_x8 (bf16, MFMA broadcast) ----
    {
        int n = nb + w; if (n >= Nn) n = Nn - 1;
        const float2 sv = *(const float2*)(u2e + (long)nodes[n] * DD + lane * 2);
        *(unsigned*)(s_x8 + w * DD + lane * 2) = pk2(sv.x, sv.y);
    }
    // epilogue self values (fp32 exact): wave w -> node (w>>1) of each iter,
    // col half (w&1)*64 + lane
    float selfs[2];
    #pragma unroll
    for (int t = 0; t < 2; ++t) {
        int gn = nb + t * 4 + (w >> 1); if (gn >= Nn) gn = Nn - 1;
        selfs[t] = u2e[(long)nodes[gn] * DD + (w & 1) * 64 + lane];
    }

    // ---- weight fragments (16 cols/wave): b1f 32 + b2f 16 VGPRs ----
    bf16x8 b1f[8], b2f[4];
    #pragma unroll
    for (int kk = 0; kk < 8; ++kk)
        b1f[kk] = *(const bf16x8*)(W1t + c * 256 + kk * 32 + q * 8);
    #pragma unroll
    for (int kk = 0; kk < 4; ++kk)
        b2f[kk] = *(const bf16x8*)(W2t + c * 128 + kk * 32 + q * 8);
    const float b1c = b1[c], b2c = b2[c], w3c = W3[c];
    const float b3v = b3[0];

    __syncthreads();   // B1 (it0): e-tile + s_x8 ready

    #pragma unroll
    for (int it = 0; it < 2; ++it) {
        unsigned short* E = it ? s_B : s_A;   // e-tile of this iter
        unsigned short* H = it ? s_A : s_B;   // h1 scratch / next stage target
        const int gbase = nb + it * 4;        // rows 0..127 = (g=row>>5, k=row&31)

        if (it == 1) __syncthreads();   // B1 (it1): s_B staged (from it0's tail)

        // ---------- layer 1: C[128 x 16/wave] = concat(e, self) x W1 ----------
        f32x4 acc[8];
        #pragma unroll
        for (int mt = 0; mt < 8; ++mt) acc[mt] = (f32x4){0.f, 0.f, 0.f, 0.f};
        #pragma unroll
        for (int kk = 0; kk < 4; ++kk) {              // e-half of the concat
            #pragma unroll
            for (int mt = 0; mt < 8; ++mt) {
                const bf16x8 a = *(const bf16x8*)(E + (mt * 16 + ln) * SE + kk * 32 + q * 8);
                acc[mt] = __builtin_amdgcn_mfma_f32_16x16x32_bf16(a, b1f[kk], acc[mt], 0, 0, 0);
            }
        }
        #pragma unroll
        for (int kk = 4; kk < 8; ++kk) {              // self-half: broadcast row
            #pragma unroll
            for (int mt = 0; mt < 8; ++mt) {
                const bf16x8 a = *(const bf16x8*)(s_x8 + (it * 4 + (mt >> 1)) * DD + (kk - 4) * 32 + q * 8);
                acc[mt] = __builtin_amdgcn_mfma_f32_16x16x32_bf16(a, b1f[kk], acc[mt], 0, 0, 0);
            }
        }
        // h1 = relu(acc + b1) -> bf16 -> H. (H's prior readers finished before
        // the last barrier: it0 -> H=s_B untouched; it1 -> s_A epilogue-read
        // completed before B1(it1).)
        #pragma unroll
        for (int mt = 0; mt < 8; ++mt) {
            #pragma unroll
            for (int rr = 0; rr < 4; rr += 2) {
                const unsigned p = pk2(fmaxf(acc[mt][rr]     + b1c, 0.f),
                                       fmaxf(acc[mt][rr + 1] + b1c, 0.f));
                const int row = mt * 16 + q * 4 + rr;
                H[row * SE + c]       = (unsigned short)(p & 0xffffu);
                H[(row + 1) * SE + c] = (unsigned short)(p >> 16);
            }
        }
        __syncthreads();   // B3: h1 ready

        // ---------- layer 2 + fused logit: h2 never touches LDS ----------
        f32x4 acc2[8];
        #pragma unroll
        for (int mt = 0; mt < 8; ++mt) acc2[mt] = (f32x4){0.f, 0.f, 0.f, 0.f};
        #pragma unroll
        for (int kk = 0; kk < 4; ++kk) {
            #pragma unroll
            for (int mt = 0; mt < 8; ++mt) {
                const bf16x8 a = *(const bf16x8*)(H + (mt * 16 + ln) * SE + kk * 32 + q * 8);
                acc2[mt] = __builtin_amdgcn_mfma_f32_16x16x32_bf16(a, b2f[kk], acc2[mt], 0, 0, 0);
            }
        }
        // per-thread logit partials reduced over the 16-lane col group
        #pragma unroll
        for (int mt = 0; mt < 8; ++mt) {
            float p[4];
            #pragma unroll
            for (int rr = 0; rr < 4; ++rr)
                p[rr] = fmaxf(acc2[mt][rr] + b2c, 0.f) * w3c;
            #pragma unroll
            for (int off = 1; off < 16; off <<= 1) {
                #pragma unroll
                for (int rr = 0; rr < 4; ++rr) p[rr] += __shfl_xor(p[rr], off);
            }
            if (ln == 0) {
                const int row0 = mt * 16 + q * 4;
                #pragma unroll
                for (int rr = 0; rr < 4; ++rr) s_part[w][row0 + rr] = p[rr];
            }
        }
        __syncthreads();   // B4: partials ready; H's (h1) readers all done

        // ---- it1 stage into s_B (free past B4): load -> immediate ds_write;
        //      latency overlaps softmax + epilogue below. ----
        if (it == 0) stage(s_B, idxB, vB);

        // ---------- masked softmax (threads 0..127; shfl within 32-groups) ----------
        if (tid < 128) {
            const int row = tid;
            float logit = b3v;
            #pragma unroll
            for (int ww = 0; ww < 8; ++ww) logit += s_part[ww][row];
            int ng = gbase + (row >> 5);
            if (ng >= Nn) ng = Nn - 1;
            const int deg = degrees[ng];
            const float ml = ((row & 31) < deg) ? logit : NEGV;
            float mx = ml;
            #pragma unroll
            for (int off = 16; off > 0; off >>= 1) mx = fmaxf(mx, __shfl_xor(mx, off));
            const float e = __expf(ml - mx);
            float ssum = e;
            #pragma unroll
            for (int off = 16; off > 0; off >>= 1) ssum += __shfl_xor(ssum, off);
            s_att[row] = e / ssum;
        }
        __syncthreads();   // B5: s_att ready

        // ---------- epilogue: aggregate from the LDS e-tile ----------
        // wave w: node nd = w>>1, col = (w&1)*64 + lane (1 col/lane, fp32 self)
        {
            const int nd = w >> 1;
            const int ng = gbase + nd;
            const int degw = (ng < Nn) ? degrees[ng] : 0;
            const int col = (w & 1) * 64 + lane;
            float ax = 0.f;
            for (int k = 0; k < degw; ++k) {
                const float a = s_att[nd * KK + k];
                ax = fmaf(a, bf2f(E[(nd * KK + k) * SE + col]), ax);
            }
            if (ng < Nn) {
                const float sv = selfs[it];
                out[(long)ng * DD + col] = (degw > 0) ? 0.5f * (ax + sv) : sv;
            }
        }
        // no trailing barrier: next iter's first touch of shared state is the
        // B1(it1) barrier at loop top (E of it1 = s_B already staged above).
    }
}

extern "C" void kernel_launch(void* const* d_in, const int* in_sizes, int n_in,
                              void* d_out, int out_size, void* d_ws, size_t ws_size,
                              hipStream_t stream) {
    const int*   nodes   = (const int*)d_in[0];
    const int*   neigh   = (const int*)d_in[1];
    const int*   degrees = (const int*)d_in[2];
    const float* u2e     = (const float*)d_in[3];
    const float* W1      = (const float*)d_in[4];
    const float* b1      = (const float*)d_in[5];
    const float* W2      = (const float*)d_in[6];
    const float* b2      = (const float*)d_in[7];
    const float* W3      = (const float*)d_in[8];
    const float* b3      = (const float*)d_in[9];
    float* out = (float*)d_out;

    const int  Nn = in_sizes[0];          // 20000
    const long Vd = (long)in_sizes[3];    // V*D = 12,800,000

    unsigned short* W1t = (unsigned short*)d_ws;        // 64 KB
    unsigned short* W2t = W1t + 256 * 128;              // 32 KB
    unsigned short* u2e_bf = W2t + 128 * 128;           // V*D bf16 = 25.6 MB

    const size_t need_bf = (size_t)(256 * 128 + 128 * 128) * 2 + (size_t)Vd * 2;
    const bool use_bf = (ws_size >= need_bf) && (Vd % 4096 == 0);
    const int u2e_blocks = use_bf ? (int)(Vd / 4096) : 0;

    prep_kernel<<<u2e_blocks + 192, 256, 0, stream>>>(u2e, W1, W2, u2e_bf, W1t, W2t, u2e_blocks);

    const int grid = (Nn + 7) / 8;
    if (use_bf)
        ppagg_mfma<true><<<grid, 512, 0, stream>>>(nodes, neigh, degrees, u2e, u2e_bf,
                                                   W1t, W2t, b1, b2, W3, b3, out, Nn);
    else
        ppagg_mfma<false><<<grid, 512, 0, stream>>>(nodes, neigh, degrees, u2e, nullptr,
                                                    W1t, W2t, b1, b2, W3, b3, out, Nn);
}

// Round 10
// 221.804 us; speedup vs baseline: 1.1406x; 1.1406x over previous
//
#include <hip/hip_runtime.h>
#include <hip/hip_bf16.h>

#define KK 32
#define DD 128
#define NEGV (-1e9f)
#define SE 136   // LDS row stride in ushorts: 272 B, 16-B aligned, non-pow2 banks

typedef __attribute__((ext_vector_type(8))) short bf16x8;
typedef __attribute__((ext_vector_type(4))) float f32x4;

__device__ __forceinline__ unsigned short f2bf(float f) {
    union { float f; unsigned u; } v; v.f = f;
    unsigned r = v.u + 0x7fffu + ((v.u >> 16) & 1u);   // RNE
    return (unsigned short)(r >> 16);
}
__device__ __forceinline__ float bf2f(unsigned short h) {
    union { unsigned u; float f; } v; v.u = ((unsigned)h) << 16;
    return v.f;
}
// packed f32x2 -> bf16x2 (v_cvt_pk_bf16_f32), RNE
__device__ __forceinline__ unsigned pk2(float x, float y) {
    union { __hip_bfloat162 h; unsigned u; } c;
    c.h = __float22bfloat162_rn(float2{x, y});
    return c.u;
}

// ---- prep (one kernel; workspace is re-poisoned each iter, so no sentinel):
//  blocks [0, u2e_blocks): u2e fp32 -> bf16, 64 B/thread (4096 els/block)
//  blocks [u2e_blocks, +192): W1 -> W1t bf16 [n][k], W2 -> W2t bf16 [n][k]
__global__ __launch_bounds__(256) void prep_kernel(
    const float* __restrict__ u2e, const float* __restrict__ W1, const float* __restrict__ W2,
    unsigned short* __restrict__ u2e_bf, unsigned short* __restrict__ W1t,
    unsigned short* __restrict__ W2t, const int u2e_blocks)
{
    const int b = blockIdx.x;
    if (b < u2e_blocks) {
        const long base = (long)b * 4096 + threadIdx.x * 16;
        const float4* s = (const float4*)(u2e + base);
        const float4 v0 = s[0], v1 = s[1], v2 = s[2], v3 = s[3];
        uint4 p0, p1;
        p0.x = pk2(v0.x, v0.y); p0.y = pk2(v0.z, v0.w);
        p0.z = pk2(v1.x, v1.y); p0.w = pk2(v1.z, v1.w);
        p1.x = pk2(v2.x, v2.y); p1.y = pk2(v2.z, v2.w);
        p1.z = pk2(v3.x, v3.y); p1.w = pk2(v3.z, v3.w);
        *(uint4*)(u2e_bf + base)     = p0;
        *(uint4*)(u2e_bf + base + 8) = p1;
    } else {
        const int id = (b - u2e_blocks) * 256 + threadIdx.x;   // 0..49151
        if (id < 256 * 128) {
            const int n = id >> 8, k = id & 255;
            W1t[id] = f2bf(W1[k * DD + n]);
        } else {
            const int j = id - 256 * 128;
            const int n = j >> 7, k = j & 127;
            W2t[j] = f2bf(W2[k * DD + n]);
        }
    }
}

template<bool BF>
__global__ __launch_bounds__(256, 2) void ppagg_mfma(
    const int* __restrict__ nodes, const int* __restrict__ neigh,
    const int* __restrict__ degrees, const float* __restrict__ u2e,
    const unsigned short* __restrict__ u2e_bf,
    const unsigned short* __restrict__ W1t, const unsigned short* __restrict__ W2t,
    const float* __restrict__ b1, const float* __restrict__ b2,
    const float* __restrict__ W3, const float* __restrict__ b3,
    float* __restrict__ out, const int Nn)
{
    // R8 structure (proven 124.7 us) + SELF-HALF HOIST: within a block, all 32
    // neighbor rows of a node share one self vector, so self.W1_self is a
    // rank-8 term -- computed ONCE per block (8 MFMA/wave prologue mini-GEMM
    // into s_selfc) instead of 64 MFMA/wave/iter. Total MFMA -33%.
    // RULE (R2/R3/R6): gathered rows NEVER live in registers across a phase.
    __shared__ __align__(16) unsigned short s_A[128 * SE];   // 34.8 KB
    __shared__ __align__(16) unsigned short s_B[128 * SE];   // 34.8 KB
    __shared__ __align__(16) unsigned short s_x8[8 * DD];    // 8 self vecs bf16 (2 KB)
    __shared__ float s_selfc[8 * 128];                        // self.W1self + b1 (4 KB)
    __shared__ float s_part[4][128];                          // per-wave logit partials
    __shared__ float s_att[128];

    const int tid  = threadIdx.x;
    const int w    = tid >> 6;     // wave id = node owner in epilogue
    const int lane = tid & 63;
    const int ln   = lane & 15;
    const int q    = lane >> 4;    // quad

    const int nb = blockIdx.x * 8;
    const int r  = tid & 127;      // staged row
    const int h  = tid >> 7;       // col half (0: 0..63, 1: 64..127)

    // ---- prologue: both iters' indices + validity ----
    // deg gating: slots k >= deg get exactly-zero attention (NEG logit ->
    // exp underflow -> att == 0.0f) -> skip their gather, stage zeros.
    int idxA, idxB, vA, vB;
    {
        int ng0 = nb + (r >> 5);       if (ng0 >= Nn) ng0 = Nn - 1;
        int ng1 = nb + 4 + (r >> 5);   if (ng1 >= Nn) ng1 = Nn - 1;
        idxA = neigh[ng0 * KK + (r & 31)];
        idxB = neigh[ng1 * KK + (r & 31)];
        vA = (r & 31) < degrees[ng0];
        vB = (r & 31) < degrees[ng1];
    }

    // ---- stage: half-row per thread, load -> immediate ds_write ----
    auto stage = [&](unsigned short* buf, int idx, int v) {
        unsigned short* dst = buf + r * SE + h * 64;
        if (BF && v) {
            const uint4* src = (const uint4*)(u2e_bf + (long)idx * DD + h * 64);
            #pragma unroll
            for (int c = 0; c < 8; ++c) *(uint4*)(dst + c * 8) = src[c];
        } else if (!BF && v) {
            const float4* src = (const float4*)(u2e + (long)idx * DD + h * 64);
            #pragma unroll
            for (int c8 = 0; c8 < 8; ++c8) {
                const float4 v0 = src[c8 * 2];
                const float4 v1 = src[c8 * 2 + 1];
                uint4 p;
                p.x = pk2(v0.x, v0.y); p.y = pk2(v0.z, v0.w);
                p.z = pk2(v1.x, v1.y); p.w = pk2(v1.z, v1.w);
                *(uint4*)(dst + c8 * 8) = p;
            }
        } else {
            const uint4 z = {0u, 0u, 0u, 0u};
            #pragma unroll
            for (int c = 0; c < 8; ++c) *(uint4*)(dst + c * 8) = z;
        }
    };

    // ---- it0 stage into s_A (issues first: longest-latency loads) ----
    stage(s_A, idxA, vA);

    // ---- all 8 self vectors -> s_x8 (bf16; feeds the prologue self-GEMM) ----
    {
        int gn = nb + (tid >> 5); if (gn >= Nn) gn = Nn - 1;
        const int g = tid >> 5, p = tid & 31;
        const float4 v = *(const float4*)(u2e + (long)nodes[gn] * DD + p * 4);
        *(unsigned*)(s_x8 + g * DD + p * 4)     = pk2(v.x, v.y);
        *(unsigned*)(s_x8 + g * DD + p * 4 + 2) = pk2(v.z, v.w);
    }

    // epilogue self values (fp32, exact): wave w owns node w of each half
    float2 self0, self1;
    {
        int n0 = nb + w;       if (n0 >= Nn) n0 = Nn - 1;
        int n1 = nb + 4 + w;   if (n1 >= Nn) n1 = Nn - 1;
        self0 = *(const float2*)(u2e + (long)nodes[n0] * DD + lane * 2);
        self1 = *(const float2*)(u2e + (long)nodes[n1] * DD + lane * 2);
    }

    // ---- weight fragments in registers (e-half of W1 only + W2) ----
    // B-frag (16x16x32): B[k = q*8+j][n = ln]; W1t/W2t are [n][k] -> contiguous 16 B
    bf16x8 b1f[4][2], b2f[4][2];
    float b1c[2], b2c[2], w3c[2];
    const int c0 = w * 32 + ln;       // owned col, nt=0
    const int c1 = c0 + 16;           // owned col, nt=1
    #pragma unroll
    for (int kk = 0; kk < 4; ++kk) {
        b1f[kk][0] = *(const bf16x8*)(W1t + c0 * 256 + kk * 32 + q * 8);
        b1f[kk][1] = *(const bf16x8*)(W1t + c1 * 256 + kk * 32 + q * 8);
        b2f[kk][0] = *(const bf16x8*)(W2t + c0 * 128 + kk * 32 + q * 8);
        b2f[kk][1] = *(const bf16x8*)(W2t + c1 * 128 + kk * 32 + q * 8);
    }
    b1c[0] = b1[c0]; b1c[1] = b1[c1];
    b2c[0] = b2[c0]; b2c[1] = b2[c1];
    w3c[0] = W3[c0]; w3c[1] = W3[c1];
    const float b3v = b3[0];

    __syncthreads();   // P1: s_x8 ready (it0 stage writes also drained)

    // ---- prologue self-GEMM: s_selfc[g][c] = self[g].W1self[:,c] + b1[c] ----
    // A rows = self vec (ln&7); C: lane q*16+ln holds rows q*4+rr, col ln.
    // Rows 8..15 are duplicates, discarded via q<2.
    {
        f32x4 a0 = (f32x4){0.f,0.f,0.f,0.f}, a1 = (f32x4){0.f,0.f,0.f,0.f};
        #pragma unroll
        for (int kk = 0; kk < 4; ++kk) {
            const bf16x8 av = *(const bf16x8*)(s_x8 + (ln & 7) * DD + kk * 32 + q * 8);
            const bf16x8 w0 = *(const bf16x8*)(W1t + c0 * 256 + 128 + kk * 32 + q * 8);
            const bf16x8 w1 = *(const bf16x8*)(W1t + c1 * 256 + 128 + kk * 32 + q * 8);
            a0 = __builtin_amdgcn_mfma_f32_16x16x32_bf16(av, w0, a0, 0, 0, 0);
            a1 = __builtin_amdgcn_mfma_f32_16x16x32_bf16(av, w1, a1, 0, 0, 0);
        }
        if (q < 2) {
            #pragma unroll
            for (int rr = 0; rr < 4; ++rr) {
                s_selfc[(q * 4 + rr) * 128 + c0] = a0[rr] + b1c[0];
                s_selfc[(q * 4 + rr) * 128 + c1] = a1[rr] + b1c[1];
            }
        }
    }
    __syncthreads();   // B1 (it0): s_selfc ready; e-tile ready since P1

    #pragma unroll
    for (int it = 0; it < 2; ++it) {
        unsigned short* E = it ? s_B : s_A;   // e-tile of this iter
        unsigned short* H = it ? s_A : s_B;   // h1 scratch of this iter
        const int gbase = nb + it * 4;        // rows 0..127 = (g=row>>5, k=row&31)
        const float2 selfv = it ? self1 : self0;

        if (it == 1) __syncthreads();   // B1 (it1): s_B staged (from it0's tail)

        // ---------- layer 1 (e-half only): C[128x128] = e[128x128] x W1e ----------
        f32x4 acc[8][2];
        #pragma unroll
        for (int mt = 0; mt < 8; ++mt) {
            acc[mt][0] = (f32x4){0.f, 0.f, 0.f, 0.f};
            acc[mt][1] = (f32x4){0.f, 0.f, 0.f, 0.f};
        }
        #pragma unroll
        for (int kk = 0; kk < 4; ++kk) {
            bf16x8 a[8];
            #pragma unroll
            for (int mt = 0; mt < 8; ++mt)
                a[mt] = *(const bf16x8*)(E + (mt * 16 + ln) * SE + kk * 32 + q * 8);
            #pragma unroll
            for (int mt = 0; mt < 8; ++mt) {
                acc[mt][0] = __builtin_amdgcn_mfma_f32_16x16x32_bf16(a[mt], b1f[kk][0], acc[mt][0], 0, 0, 0);
                acc[mt][1] = __builtin_amdgcn_mfma_f32_16x16x32_bf16(a[mt], b1f[kk][1], acc[mt][1], 0, 0, 0);
            }
        }
        // h1 = relu(acc + selfc(node,col)) -> bf16 -> H  (selfc includes b1;
        // node of rows [mt*16, mt*16+15] = mt>>1). No barrier needed before H
        // writes: H's previous readers finished before the last barrier.
        #pragma unroll
        for (int mt = 0; mt < 8; ++mt) {
            const float sc0 = s_selfc[(it * 4 + (mt >> 1)) * 128 + c0];
            const float sc1 = s_selfc[(it * 4 + (mt >> 1)) * 128 + c1];
            #pragma unroll
            for (int rr = 0; rr < 4; rr += 2) {
                const int row = mt * 16 + q * 4 + rr;
                const unsigned p0 = pk2(fmaxf(acc[mt][0][rr]     + sc0, 0.f),
                                        fmaxf(acc[mt][0][rr + 1] + sc0, 0.f));
                const unsigned p1v = pk2(fmaxf(acc[mt][1][rr]     + sc1, 0.f),
                                         fmaxf(acc[mt][1][rr + 1] + sc1, 0.f));
                H[row * SE + c0]       = (unsigned short)(p0 & 0xffffu);
                H[(row + 1) * SE + c0] = (unsigned short)(p0 >> 16);
                H[row * SE + c1]       = (unsigned short)(p1v & 0xffffu);
                H[(row + 1) * SE + c1] = (unsigned short)(p1v >> 16);
            }
        }
        __syncthreads();   // B3: h1 ready

        // ---------- layer 2 + fused logit: h2 never touches LDS ----------
        f32x4 acc2[8][2];
        #pragma unroll
        for (int mt = 0; mt < 8; ++mt) {
            acc2[mt][0] = (f32x4){0.f, 0.f, 0.f, 0.f};
            acc2[mt][1] = (f32x4){0.f, 0.f, 0.f, 0.f};
        }
        #pragma unroll
        for (int kk = 0; kk < 4; ++kk) {
            bf16x8 a[8];
            #pragma unroll
            for (int mt = 0; mt < 8; ++mt)
                a[mt] = *(const bf16x8*)(H + (mt * 16 + ln) * SE + kk * 32 + q * 8);
            #pragma unroll
            for (int mt = 0; mt < 8; ++mt) {
                acc2[mt][0] = __builtin_amdgcn_mfma_f32_16x16x32_bf16(a[mt], b2f[kk][0], acc2[mt][0], 0, 0, 0);
                acc2[mt][1] = __builtin_amdgcn_mfma_f32_16x16x32_bf16(a[mt], b2f[kk][1], acc2[mt][1], 0, 0, 0);
            }
        }
        // per-thread logit partials reduced over the 16-lane col group
        #pragma unroll
        for (int mt = 0; mt < 8; ++mt) {
            float p[4];
            #pragma unroll
            for (int rr = 0; rr < 4; ++rr) {
                const float h0 = fmaxf(acc2[mt][0][rr] + b2c[0], 0.f);
                const float h1v = fmaxf(acc2[mt][1][rr] + b2c[1], 0.f);
                p[rr] = fmaf(h0, w3c[0], h1v * w3c[1]);
            }
            #pragma unroll
            for (int off = 1; off < 16; off <<= 1) {
                #pragma unroll
                for (int rr = 0; rr < 4; ++rr) p[rr] += __shfl_xor(p[rr], off);
            }
            if (ln == 0) {
                const int row0 = mt * 16 + q * 4;
                #pragma unroll
                for (int rr = 0; rr < 4; ++rr) s_part[w][row0 + rr] = p[rr];
            }
        }
        __syncthreads();   // B4: partials ready; H's (h1) readers all done

        // ---- it1 stage into s_B (free past B4): load -> immediate ds_write;
        //      latency overlaps softmax + epilogue below. ----
        if (it == 0) stage(s_B, idxB, vB);

        // ---------- masked softmax (threads 0..127; shfl within 32-groups) ----------
        if (tid < 128) {
            const int row = tid;
            const float logit = s_part[0][row] + s_part[1][row] + s_part[2][row] + s_part[3][row] + b3v;
            int ng = gbase + (row >> 5);
            if (ng >= Nn) ng = Nn - 1;
            const int deg = degrees[ng];
            const float ml = ((row & 31) < deg) ? logit : NEGV;
            float mx = ml;
            #pragma unroll
            for (int off = 16; off > 0; off >>= 1) mx = fmaxf(mx, __shfl_xor(mx, off));
            const float e = __expf(ml - mx);
            float ssum = e;
            #pragma unroll
            for (int off = 16; off > 0; off >>= 1) ssum += __shfl_xor(ssum, off);
            s_att[row] = e / ssum;
        }
        __syncthreads();   // B5: s_att ready

        // ---------- epilogue: aggregation straight from the LDS e-tile ----------
        {
            const int ng = gbase + w;
            const int degw = (ng < Nn) ? degrees[ng] : 0;
            float ax = 0.f, ay = 0.f;
            for (int k = 0; k < degw; ++k) {
                const float a = s_att[w * KK + k];
                const unsigned pe = *(const unsigned*)(E + (w * KK + k) * SE + lane * 2);
                ax = fmaf(a, bf2f((unsigned short)(pe & 0xffffu)), ax);
                ay = fmaf(a, bf2f((unsigned short)(pe >> 16)), ay);
            }
            if (ng < Nn) {
                float2 o;
                o.x = (degw > 0) ? 0.5f * (ax + selfv.x) : selfv.x;
                o.y = (degw > 0) ? 0.5f * (ay + selfv.y) : selfv.y;
                *(float2*)(out + (long)ng * DD + lane * 2) = o;
            }
        }
        // no trailing barrier: next iter's first touch of shared state is the
        // B1(it1) barrier at loop top (E of it1 = s_B already staged above).
    }
}

extern "C" void kernel_launch(void* const* d_in, const int* in_sizes, int n_in,
                              void* d_out, int out_size, void* d_ws, size_t ws_size,
                              hipStream_t stream) {
    const int*   nodes   = (const int*)d_in[0];
    const int*   neigh   = (const int*)d_in[1];
    const int*   degrees = (const int*)d_in[2];
    const float* u2e     = (const float*)d_in[3];
    const float* W1      = (const float*)d_in[4];
    const float* b1      = (const float*)d_in[5];
    const float* W2      = (const float*)d_in[6];
    const float* b2      = (const float*)d_in[7];
    const float* W3      = (const float*)d_in[8];
    const float* b3      = (const float*)d_in[9];
    float* out = (float*)d_out;

    const int  Nn = in_sizes[0];          // 20000
    const long Vd = (long)in_sizes[3];    // V*D = 12,800,000

    unsigned short* W1t = (unsigned short*)d_ws;        // 64 KB
    unsigned short* W2t = W1t + 256 * 128;              // 32 KB
    unsigned short* u2e_bf = W2t + 128 * 128;           // V*D bf16 = 25.6 MB

    const size_t need_bf = (size_t)(256 * 128 + 128 * 128) * 2 + (size_t)Vd * 2;
    const bool use_bf = (ws_size >= need_bf) && (Vd % 4096 == 0);
    const int u2e_blocks = use_bf ? (int)(Vd / 4096) : 0;

    prep_kernel<<<u2e_blocks + 192, 256, 0, stream>>>(u2e, W1, W2, u2e_bf, W1t, W2t, u2e_blocks);

    const int grid = (Nn + 7) / 8;
    if (use_bf)
        ppagg_mfma<true><<<grid, 256, 0, stream>>>(nodes, neigh, degrees, u2e, u2e_bf,
                                                   W1t, W2t, b1, b2, W3, b3, out, Nn);
    else
        ppagg_mfma<false><<<grid, 256, 0, stream>>>(nodes, neigh, degrees, u2e, nullptr,
                                                    W1t, W2t, b1, b2, W3, b3, out, Nn);
}